// Round 3
// baseline (136.812 us; speedup 1.0000x reference)
//
#include <hip/hip_runtime.h>

#define NN 256
#define DD 128
#define OC 128
// pre layout per row: [ preA+bm1 (128) | preB (128) | h@Wu_top (128) ] = 384 f32

__device__ __forceinline__ float bcastf(float x, int lane) {
    return __int_as_float(__builtin_amdgcn_readlane(__float_as_int(x), lane));
}

// ---------------------------------------------------------------------------
// K1: wave-per-row GEMV. pre = h @ [Wm1_top | Wm1_bot | Wu_top]; ai/aj dots.
// Lane l owns col-pair (2l,2l+1) of each 128-col region. h row broadcast via
// readlane. No LDS, no barriers.
// ---------------------------------------------------------------------------
__global__ __launch_bounds__(256) void k1_pre(
    const float* __restrict__ h, const float* __restrict__ Wm1,
    const float* __restrict__ Wa, const float* __restrict__ bm1,
    const float* __restrict__ Wu, const float* __restrict__ ba,
    float* __restrict__ pre, float* __restrict__ aiv, float* __restrict__ ajv)
{
    const int tid = threadIdx.x;
    const int l   = tid & 63;
    const int w   = tid >> 6;
    const int row = blockIdx.x * 4 + w;

    const float2* h2v   = (const float2*)h;
    const float2* Wm1_2 = (const float2*)Wm1;
    const float2* Wu_2  = (const float2*)Wu;
    const float2* Wa2   = (const float2*)Wa;

    const float2 hl = h2v[row * 64 + l];

    // attention dot products: butterfly reduce over the wave
    {
        const float2 wt = Wa2[l], wb = Wa2[64 + l];
        float vi = hl.x * wt.x + hl.y * wt.y;
        float vj = hl.x * wb.x + hl.y * wb.y;
        #pragma unroll
        for (int o = 1; o < 64; o <<= 1) {
            vi += __shfl_xor(vi, o, 64);
            vj += __shfl_xor(vj, o, 64);
        }
        if (l == 0) { aiv[row] = vi + ba[0]; ajv[row] = vj; }
    }

    float2 c0{0.f,0.f}, c1{0.f,0.f}, c2{0.f,0.f};
    #pragma unroll 4
    for (int m = 0; m < 64; ++m) {
        const float hx = bcastf(hl.x, m);          // h[row][2m]
        const float hy = bcastf(hl.y, m);          // h[row][2m+1]
        const int d0 = 2 * m, d1 = 2 * m + 1;
        const float2 a00 = Wm1_2[d0 * 64 + l],        a01 = Wm1_2[d1 * 64 + l];
        const float2 b00 = Wm1_2[(DD + d0) * 64 + l], b01 = Wm1_2[(DD + d1) * 64 + l];
        const float2 u00 = Wu_2[d0 * 64 + l],         u01 = Wu_2[d1 * 64 + l];
        c0.x = fmaf(hx, a00.x, fmaf(hy, a01.x, c0.x));
        c0.y = fmaf(hx, a00.y, fmaf(hy, a01.y, c0.y));
        c1.x = fmaf(hx, b00.x, fmaf(hy, b01.x, c1.x));
        c1.y = fmaf(hx, b00.y, fmaf(hy, b01.y, c1.y));
        c2.x = fmaf(hx, u00.x, fmaf(hy, u01.x, c2.x));
        c2.y = fmaf(hx, u00.y, fmaf(hy, u01.y, c2.y));
    }
    const float2 bb = ((const float2*)bm1)[l];
    c0.x += bb.x; c0.y += bb.y;

    float2* pre2 = (float2*)pre;
    const int rb = row * 192;
    pre2[rb + l]       = c0;
    pre2[rb + 64 + l]  = c1;
    pre2[rb + 128 + l] = c2;
}

// ---------------------------------------------------------------------------
// K2: block = 4 waves = 2 rows x 2 j-halves. Lane l owns j = jb+2l, jb+2l+1.
// Softmax: butterfly within wave + tiny LDS cross-wave combine (2 barriers).
// Active j ballot-compacted into lane registers; phase-B loop is branch-free:
// readlane-broadcast (w,d,joff) + coalesced preB float2 load + 8 VALU.
// ---------------------------------------------------------------------------
__global__ __launch_bounds__(256) void k2_main(
    const int* __restrict__ adj, const float* __restrict__ dist,
    const float* __restrict__ Wm1, const float* __restrict__ Wa,
    const float* __restrict__ pre,
    const float* __restrict__ aiv, const float* __restrict__ ajv,
    float* __restrict__ tmat, float* __restrict__ sflag)
{
    const int tid  = threadIdx.x;
    const int l    = tid & 63;
    const int wid  = tid >> 6;
    const int r    = wid >> 1;          // row within block
    const int half = wid & 1;           // j-half
    const int row  = blockIdx.x * 2 + r;
    const int b    = row >> 8;

    __shared__ float  mx_sh[4], sm_sh[4];
    __shared__ float4 cw[4][128];
    __shared__ float2 accb[2][64];

    const int   jb  = half * 128;
    const int2  mk2 = ((const int2*)  (adj  + row * NN))[half * 64 + l];
    const float2 dv2 = ((const float2*)(dist + row * NN))[half * 64 + l];
    const float2 aj2 = ((const float2*)(ajv  + b   * NN))[half * 64 + l];
    const float ai = aiv[row];
    const float dc = Wa[2 * DD];

    float l0 = ai + aj2.x + dv2.x * dc;
    float l1 = ai + aj2.y + dv2.y * dc;
    l0 = (l0 >= 0.f) ? l0 : 0.2f * l0;
    l1 = (l1 >= 0.f) ? l1 : 0.2f * l1;
    const float l0m = mk2.x ? l0 : -1e9f;
    const float l1m = mk2.y ? l1 : -1e9f;

    float m = fmaxf(l0m, l1m);
    #pragma unroll
    for (int o = 1; o < 64; o <<= 1) m = fmaxf(m, __shfl_xor(m, o, 64));
    if (l == 0) mx_sh[wid] = m;
    __syncthreads();
    const float mx = fmaxf(mx_sh[r * 2], mx_sh[r * 2 + 1]);

    const float e0 = mk2.x ? __expf(l0 - mx) : 0.f;
    const float e1 = mk2.y ? __expf(l1 - mx) : 0.f;
    float s = e0 + e1;
    #pragma unroll
    for (int o = 1; o < 64; o <<= 1) s += __shfl_xor(s, o, 64);
    if (l == 0) sm_sh[wid] = s;
    __syncthreads();
    const float esum = sm_sh[r * 2] + sm_sh[r * 2 + 1];
    const float inv  = (esum > 0.f) ? (1.0f / esum) : 0.f;
    const float w0 = e0 * inv, w1 = e1 * inv;

    // ballot-compact active j of this wave's half into cw[wid][0..cnt)
    const unsigned long long below = (1ull << l) - 1ull;
    const unsigned long long m0 = __ballot(w0 != 0.f);
    const unsigned long long m1 = __ballot(w1 != 0.f);
    const int c0n = __popcll(m0);
    const int cnt = c0n + __popcll(m1);
    const int j0 = jb + 2 * l;
    if (w0 != 0.f)
        cw[wid][__popcll(m0 & below)]       = make_float4(w0, dv2.x, __int_as_float(j0 * 192), 0.f);
    if (w1 != 0.f)
        cw[wid][c0n + __popcll(m1 & below)] = make_float4(w1, dv2.y, __int_as_float((j0 + 1) * 192), 0.f);
    __syncthreads();
    const float4 g0 = cw[wid][l];
    const float4 g1 = cw[wid][64 + l];

    const float2* pre2 = (const float2*)pre;
    const float2  pa   = pre2[row * 192 + l];                      // preA'+bm1
    const float2  wd1  = ((const float2*)Wm1)[(2 * DD * OC) / 2 + l]; // d-coef
    const float2* pBb  = pre2 + (size_t)b * NN * 192 + 64;         // preB region

    float2 acc{0.f, 0.f};
    const int n0 = cnt < 64 ? cnt : 64;
    for (int p = 0; p < n0; ++p) {
        const float wp  = bcastf(g0.x, p);
        const float dp  = bcastf(g0.y, p);
        const int   jof = __builtin_amdgcn_readlane(__float_as_int(g0.z), p);
        const float2 pb = pBb[jof + l];
        const float vx = fmaf(dp, wd1.x, pa.x + pb.x);
        const float vy = fmaf(dp, wd1.y, pa.y + pb.y);
        acc.x = fmaf(wp, fmaxf(vx, 0.f), acc.x);
        acc.y = fmaf(wp, fmaxf(vy, 0.f), acc.y);
    }
    for (int p = 64; p < cnt; ++p) {
        const float wp  = bcastf(g1.x, p - 64);
        const float dp  = bcastf(g1.y, p - 64);
        const int   jof = __builtin_amdgcn_readlane(__float_as_int(g1.z), p - 64);
        const float2 pb = pBb[jof + l];
        const float vx = fmaf(dp, wd1.x, pa.x + pb.x);
        const float vy = fmaf(dp, wd1.y, pa.y + pb.y);
        acc.x = fmaf(wp, fmaxf(vx, 0.f), acc.x);
        acc.y = fmaf(wp, fmaxf(vy, 0.f), acc.y);
    }

    if (half == 1) accb[r][l] = acc;
    __syncthreads();
    if (half == 0) {
        const float2 o = accb[r][l];
        float2 t{acc.x + o.x, acc.y + o.y};
        ((float2*)tmat)[row * 64 + l] = t;
        if (l == 0) sflag[row] = (esum > 0.f) ? 1.f : 0.f;
    }
}

// ---------------------------------------------------------------------------
// K3: wave-per-row. agg = t@Wm2 + bm2*sf; out = relu(hu + agg@Wu_bot + bu).
// Same readlane-broadcast GEMV pattern; no LDS, no barriers.
// ---------------------------------------------------------------------------
__global__ __launch_bounds__(256) void k3_out(
    const float* __restrict__ tmat, const float* __restrict__ sflag,
    const float* __restrict__ pre,
    const float* __restrict__ Wm2, const float* __restrict__ bm2,
    const float* __restrict__ Wu,  const float* __restrict__ bu,
    float* __restrict__ out)
{
    const int tid = threadIdx.x;
    const int l   = tid & 63;
    const int w   = tid >> 6;
    const int row = blockIdx.x * 4 + w;

    const float2* Wm2_2 = (const float2*)Wm2;
    const float2* Wu_2  = (const float2*)Wu;
    const float2 t2 = ((const float2*)tmat)[row * 64 + l];
    const float  sf = sflag[row];

    float2 a{0.f, 0.f};
    #pragma unroll 4
    for (int m = 0; m < 64; ++m) {
        const float tx = bcastf(t2.x, m);
        const float ty = bcastf(t2.y, m);
        const float2 q0 = Wm2_2[(2 * m) * 64 + l], q1 = Wm2_2[(2 * m + 1) * 64 + l];
        a.x = fmaf(tx, q0.x, fmaf(ty, q1.x, a.x));
        a.y = fmaf(tx, q0.y, fmaf(ty, q1.y, a.y));
    }
    const float2 b2 = ((const float2*)bm2)[l];
    a.x = fmaf(b2.x, sf, a.x);
    a.y = fmaf(b2.y, sf, a.y);

    float2 o{0.f, 0.f};
    #pragma unroll 4
    for (int m = 0; m < 64; ++m) {
        const float ax = bcastf(a.x, m);
        const float ay = bcastf(a.y, m);
        const float2 q0 = Wu_2[(DD + 2 * m) * 64 + l], q1 = Wu_2[(DD + 2 * m + 1) * 64 + l];
        o.x = fmaf(ax, q0.x, fmaf(ay, q1.x, o.x));
        o.y = fmaf(ax, q0.y, fmaf(ay, q1.y, o.y));
    }
    const float2 hu = ((const float2*)pre)[row * 192 + 128 + l];
    const float2 bl = ((const float2*)bu)[l];
    float2 res{fmaxf(o.x + hu.x + bl.x, 0.f), fmaxf(o.y + hu.y + bl.y, 0.f)};
    ((float2*)out)[row * 64 + l] = res;
}

extern "C" void kernel_launch(void* const* d_in, const int* in_sizes, int n_in,
                              void* d_out, int out_size, void* d_ws, size_t ws_size,
                              hipStream_t stream) {
    const float* h    = (const float*)d_in[0];
    const int*   adj  = (const int*)  d_in[1];
    const float* dist = (const float*)d_in[2];
    const float* Wm1  = (const float*)d_in[3];
    const float* bm1  = (const float*)d_in[4];
    const float* Wm2  = (const float*)d_in[5];
    const float* bm2  = (const float*)d_in[6];
    const float* Wa   = (const float*)d_in[7];
    const float* ba   = (const float*)d_in[8];
    const float* Wu   = (const float*)d_in[9];
    const float* bu   = (const float*)d_in[10];
    float* out = (float*)d_out;

    float* pre  = (float*)d_ws;                   // 2048*384 f32 = 3 MB
    float* aiv  = pre + 2048 * 384;               // 2048
    float* ajv  = aiv + 2048;                     // 2048
    float* tmat = ajv + 2048;                     // 2048*128 = 1 MB
    float* sfl  = tmat + 2048 * 128;              // 2048

    k1_pre <<<512,  256, 0, stream>>>(h, Wm1, Wa, bm1, Wu, ba, pre, aiv, ajv);
    k2_main<<<1024, 256, 0, stream>>>(adj, dist, Wm1, Wa, pre, aiv, ajv, tmat, sfl);
    k3_out <<<512,  256, 0, stream>>>(tmat, sfl, pre, Wm2, bm2, Wu, bu, out);
}

// Round 4
// 132.160 us; speedup vs baseline: 1.0352x; 1.0352x over previous
//
#include <hip/hip_runtime.h>

#define NN 256
#define DD 128
#define OC 128
// pre layout per row: [ preA+bm1 (128) | preB (128) | h@Wu_top (128) ] = 384 f32

__device__ __forceinline__ float bcastf(float x, int lane) {
    return __int_as_float(__builtin_amdgcn_readlane(__float_as_int(x), lane));
}

// ---------------------------------------------------------------------------
// K1: block = 4 rows, 4 waves. Wave w in {0,1,2} computes one 128-col region
// for ALL 4 rows (weight float2 loaded once, h broadcast via readlane);
// wave 3 computes ai/aj dot products. No LDS, no barriers.
// Regions: 0 = h@Wm1_top + bm1, 1 = h@Wm1_bot, 2 = h@Wu_top.
// ---------------------------------------------------------------------------
__global__ __launch_bounds__(256) void k1_pre(
    const float* __restrict__ h, const float* __restrict__ Wm1,
    const float* __restrict__ Wa, const float* __restrict__ bm1,
    const float* __restrict__ Wu, const float* __restrict__ ba,
    float* __restrict__ pre, float* __restrict__ aiv, float* __restrict__ ajv)
{
    const int tid  = threadIdx.x;
    const int l    = tid & 63;
    const int w    = tid >> 6;
    const int row0 = blockIdx.x * 4;

    const float2* h2 = (const float2*)h;
    float2 hr[4];
    #pragma unroll
    for (int r = 0; r < 4; ++r) hr[r] = h2[(row0 + r) * 64 + l];

    if (w == 3) {
        // ai = h@Wa_top + ba, aj = h@Wa_bot for 4 rows
        const float2* Wa2 = (const float2*)Wa;
        const float2 wt = Wa2[l], wb = Wa2[64 + l];
        float vi[4], vj[4];
        #pragma unroll
        for (int r = 0; r < 4; ++r) {
            vi[r] = hr[r].x * wt.x + hr[r].y * wt.y;
            vj[r] = hr[r].x * wb.x + hr[r].y * wb.y;
        }
        #pragma unroll
        for (int o = 1; o < 64; o <<= 1) {
            #pragma unroll
            for (int r = 0; r < 4; ++r) {
                vi[r] += __shfl_xor(vi[r], o, 64);
                vj[r] += __shfl_xor(vj[r], o, 64);
            }
        }
        if (l == 0) {
            const float b0 = ba[0];
            #pragma unroll
            for (int r = 0; r < 4; ++r) {
                aiv[row0 + r] = vi[r] + b0;
                ajv[row0 + r] = vj[r];
            }
        }
        return;
    }

    const float2* W2 = (w == 0) ? (const float2*)Wm1
                     : (w == 1) ? (const float2*)Wm1 + DD * 64
                                : (const float2*)Wu;

    float2 acc[4];
    #pragma unroll
    for (int r = 0; r < 4; ++r) acc[r] = make_float2(0.f, 0.f);

    #pragma unroll 4
    for (int m = 0; m < 64; ++m) {
        const float2 w0 = W2[(2 * m) * 64 + l];
        const float2 w1 = W2[(2 * m + 1) * 64 + l];
        #pragma unroll
        for (int r = 0; r < 4; ++r) {
            const float hx = bcastf(hr[r].x, m);
            const float hy = bcastf(hr[r].y, m);
            acc[r].x = fmaf(hx, w0.x, fmaf(hy, w1.x, acc[r].x));
            acc[r].y = fmaf(hx, w0.y, fmaf(hy, w1.y, acc[r].y));
        }
    }
    if (w == 0) {
        const float2 bb = ((const float2*)bm1)[l];
        #pragma unroll
        for (int r = 0; r < 4; ++r) { acc[r].x += bb.x; acc[r].y += bb.y; }
    }
    float2* pre2 = (float2*)pre;
    #pragma unroll
    for (int r = 0; r < 4; ++r)
        pre2[(row0 + r) * 192 + w * 64 + l] = acc[r];
}

// ---------------------------------------------------------------------------
// K2 (fused): block = 4 rows, wave w = row w. Per wave:
//  - register-only masked softmax over 256 j (lane owns j = 4l..4l+3)
//  - phase B: t[2l..2l+1] = sum_j w_j*relu(pa + preB[j] + d_j*wd1), active j
//    only via wave-uniform scalar branch (w_j broadcast by readlane)
//  - t -> LDS; then agg = t@Wm2 + bm2*sf and out = relu(hu + agg@Wu_bot + bu)
//    computed col-split across the 4 waves (weights read once per 4 rows).
// ---------------------------------------------------------------------------
__global__ __launch_bounds__(256) void k2_main(
    const int* __restrict__ adj, const float* __restrict__ dist,
    const float* __restrict__ Wm1, const float* __restrict__ Wa,
    const float* __restrict__ pre,
    const float* __restrict__ aiv, const float* __restrict__ ajv,
    const float* __restrict__ Wm2, const float* __restrict__ bm2,
    const float* __restrict__ Wu,  const float* __restrict__ bu,
    float* __restrict__ out)
{
    const int tid  = threadIdx.x;
    const int l    = tid & 63;
    const int w    = tid >> 6;           // row within block
    const int row0 = blockIdx.x * 4;
    const int row  = row0 + w;
    const int b    = row >> 8;

    __shared__ float t_sh[4][128];
    __shared__ float agg_sh[4][128];
    __shared__ float sf_sh[4];

    // ---- softmax over j (register-only) ----
    const int4   mk4 = ((const int4*)  (adj  + row * NN))[l];
    const float4 dv4 = ((const float4*)(dist + row * NN))[l];
    const float4 aj4 = ((const float4*)(ajv  + b   * NN))[l];
    const float  ai  = aiv[row];
    const float  dc  = Wa[2 * DD];

    float lg[4];
    lg[0] = ai + aj4.x + dv4.x * dc;
    lg[1] = ai + aj4.y + dv4.y * dc;
    lg[2] = ai + aj4.z + dv4.z * dc;
    lg[3] = ai + aj4.w + dv4.w * dc;
    #pragma unroll
    for (int c = 0; c < 4; ++c) lg[c] = (lg[c] >= 0.f) ? lg[c] : 0.2f * lg[c];
    const int mk[4] = {mk4.x, mk4.y, mk4.z, mk4.w};

    float m = -1e9f;
    #pragma unroll
    for (int c = 0; c < 4; ++c) if (mk[c]) m = fmaxf(m, lg[c]);
    #pragma unroll
    for (int o = 1; o < 64; o <<= 1) m = fmaxf(m, __shfl_xor(m, o, 64));

    float e[4], s = 0.f;
    #pragma unroll
    for (int c = 0; c < 4; ++c) { e[c] = mk[c] ? __expf(lg[c] - m) : 0.f; s += e[c]; }
    #pragma unroll
    for (int o = 1; o < 64; o <<= 1) s += __shfl_xor(s, o, 64);
    const float inv = (s > 0.f) ? (1.0f / s) : 0.f;
    float wj0 = e[0] * inv, wj1 = e[1] * inv, wj2 = e[2] * inv, wj3 = e[3] * inv;

    // ---- phase B ----
    const float2* pre2 = (const float2*)pre;
    const float2  pa   = pre2[row * 192 + l];                       // preA+bm1
    const float2  wd1  = ((const float2*)Wm1)[2 * DD * 64 + l];     // d-coef row
    const float2* pBb  = pre2 + (size_t)b * NN * 192 + 64;          // preB region

    float2 acc = make_float2(0.f, 0.f);
    for (int p = 0; p < 64; ++p) {
        const float sw0 = bcastf(wj0, p), sd0 = bcastf(dv4.x, p);
        const float sw1 = bcastf(wj1, p), sd1 = bcastf(dv4.y, p);
        const float sw2 = bcastf(wj2, p), sd2 = bcastf(dv4.z, p);
        const float sw3 = bcastf(wj3, p), sd3 = bcastf(dv4.w, p);
        const int jb = 4 * p;
        if (sw0 != 0.f) {
            const float2 pb = pBb[jb * 192 + l];
            const float vx = fmaf(sd0, wd1.x, pa.x + pb.x);
            const float vy = fmaf(sd0, wd1.y, pa.y + pb.y);
            acc.x = fmaf(sw0, fmaxf(vx, 0.f), acc.x);
            acc.y = fmaf(sw0, fmaxf(vy, 0.f), acc.y);
        }
        if (sw1 != 0.f) {
            const float2 pb = pBb[(jb + 1) * 192 + l];
            const float vx = fmaf(sd1, wd1.x, pa.x + pb.x);
            const float vy = fmaf(sd1, wd1.y, pa.y + pb.y);
            acc.x = fmaf(sw1, fmaxf(vx, 0.f), acc.x);
            acc.y = fmaf(sw1, fmaxf(vy, 0.f), acc.y);
        }
        if (sw2 != 0.f) {
            const float2 pb = pBb[(jb + 2) * 192 + l];
            const float vx = fmaf(sd2, wd1.x, pa.x + pb.x);
            const float vy = fmaf(sd2, wd1.y, pa.y + pb.y);
            acc.x = fmaf(sw2, fmaxf(vx, 0.f), acc.x);
            acc.y = fmaf(sw2, fmaxf(vy, 0.f), acc.y);
        }
        if (sw3 != 0.f) {
            const float2 pb = pBb[(jb + 3) * 192 + l];
            const float vx = fmaf(sd3, wd1.x, pa.x + pb.x);
            const float vy = fmaf(sd3, wd1.y, pa.y + pb.y);
            acc.x = fmaf(sw3, fmaxf(vx, 0.f), acc.x);
            acc.y = fmaf(sw3, fmaxf(vy, 0.f), acc.y);
        }
    }
    t_sh[w][2 * l]     = acc.x;
    t_sh[w][2 * l + 1] = acc.y;
    if (l == 0) sf_sh[w] = (s > 0.f) ? 1.f : 0.f;
    __syncthreads();

    // ---- agg = t @ Wm2 + bm2*sf, col-split: wave w owns cols [32w,32w+32) ----
    const int c   = 32 * w + (l & 31);
    const int rsl = l >> 5;
    float a[2];
    #pragma unroll
    for (int pass = 0; pass < 2; ++pass) {
        const int r = 2 * pass + rsl;
        float av = 0.f;
        #pragma unroll 8
        for (int k = 0; k < 128; ++k)
            av = fmaf(t_sh[r][k], Wm2[k * OC + c], av);
        a[pass] = fmaf(bm2[c], sf_sh[r], av);
    }
    #pragma unroll
    for (int pass = 0; pass < 2; ++pass)
        agg_sh[2 * pass + rsl][c] = a[pass];
    __syncthreads();

    // ---- out = relu(hu + agg @ Wu_bot + bu) ----
    const float buc = bu[c];
    #pragma unroll
    for (int pass = 0; pass < 2; ++pass) {
        const int r = 2 * pass + rsl;
        float ov = 0.f;
        #pragma unroll 8
        for (int k = 0; k < 128; ++k)
            ov = fmaf(agg_sh[r][k], Wu[(DD + k) * OC + c], ov);
        const float hu = pre[(row0 + r) * 384 + 256 + c];
        out[(row0 + r) * OC + c] = fmaxf(ov + hu + buc, 0.f);
    }
}

extern "C" void kernel_launch(void* const* d_in, const int* in_sizes, int n_in,
                              void* d_out, int out_size, void* d_ws, size_t ws_size,
                              hipStream_t stream) {
    const float* h    = (const float*)d_in[0];
    const int*   adj  = (const int*)  d_in[1];
    const float* dist = (const float*)d_in[2];
    const float* Wm1  = (const float*)d_in[3];
    const float* bm1  = (const float*)d_in[4];
    const float* Wm2  = (const float*)d_in[5];
    const float* bm2  = (const float*)d_in[6];
    const float* Wa   = (const float*)d_in[7];
    const float* ba   = (const float*)d_in[8];
    const float* Wu   = (const float*)d_in[9];
    const float* bu   = (const float*)d_in[10];
    float* out = (float*)d_out;

    float* pre = (float*)d_ws;                    // 2048*384 f32 = 3 MB
    float* aiv = pre + 2048 * 384;                // 2048
    float* ajv = aiv + 2048;                      // 2048

    k1_pre <<<512, 256, 0, stream>>>(h, Wm1, Wa, bm1, Wu, ba, pre, aiv, ajv);
    k2_main<<<512, 256, 0, stream>>>(adj, dist, Wm1, Wa, pre, aiv, ajv,
                                     Wm2, bm2, Wu, bu, out);
}

// Round 5
// 116.395 us; speedup vs baseline: 1.1754x; 1.1354x over previous
//
#include <hip/hip_runtime.h>

#define NN 256
#define DD 128
#define OC 128
// pre layout per row: [ preA+bm1 (128) | preB (128) | h@Wu_top (128) ] = 384 f32

__device__ __forceinline__ float bcastf(float x, int lane) {
    return __int_as_float(__builtin_amdgcn_readlane(__float_as_int(x), lane));
}

// ---------------------------------------------------------------------------
// K1: 1024 blocks x 4 waves; block = 2 rows. Wave w in {0,1,2} computes one
// 128-col region for both rows (weights float2-streamed, h broadcast via
// readlane); wave 3 computes ai/aj. No LDS, no barriers.
// Regions: 0 = h@Wm1_top + bm1, 1 = h@Wm1_bot, 2 = h@Wu_top.
// ---------------------------------------------------------------------------
__global__ __launch_bounds__(256) void k1_pre(
    const float* __restrict__ h, const float* __restrict__ Wm1,
    const float* __restrict__ Wa, const float* __restrict__ bm1,
    const float* __restrict__ Wu, const float* __restrict__ ba,
    float* __restrict__ pre, float* __restrict__ aiv, float* __restrict__ ajv)
{
    const int tid  = threadIdx.x;
    const int l    = tid & 63;
    const int w    = tid >> 6;
    const int row0 = blockIdx.x * 2;

    const float2* h2 = (const float2*)h;
    float2 hr[2];
    hr[0] = h2[row0 * 64 + l];
    hr[1] = h2[(row0 + 1) * 64 + l];

    if (w == 3) {
        const float2* Wa2 = (const float2*)Wa;
        const float2 wt = Wa2[l], wb = Wa2[64 + l];
        float vi[2], vj[2];
        #pragma unroll
        for (int r = 0; r < 2; ++r) {
            vi[r] = hr[r].x * wt.x + hr[r].y * wt.y;
            vj[r] = hr[r].x * wb.x + hr[r].y * wb.y;
        }
        #pragma unroll
        for (int o = 1; o < 64; o <<= 1) {
            #pragma unroll
            for (int r = 0; r < 2; ++r) {
                vi[r] += __shfl_xor(vi[r], o, 64);
                vj[r] += __shfl_xor(vj[r], o, 64);
            }
        }
        if (l == 0) {
            const float b0 = ba[0];
            #pragma unroll
            for (int r = 0; r < 2; ++r) {
                aiv[row0 + r] = vi[r] + b0;
                ajv[row0 + r] = vj[r];
            }
        }
        return;
    }

    const float2* W2 = (w == 0) ? (const float2*)Wm1
                     : (w == 1) ? (const float2*)Wm1 + DD * 64
                                : (const float2*)Wu;

    float2 acc[2] = {{0.f, 0.f}, {0.f, 0.f}};
    #pragma unroll 8
    for (int m = 0; m < 64; ++m) {
        const float2 w0 = W2[(2 * m) * 64 + l];
        const float2 w1 = W2[(2 * m + 1) * 64 + l];
        #pragma unroll
        for (int r = 0; r < 2; ++r) {
            const float hx = bcastf(hr[r].x, m);
            const float hy = bcastf(hr[r].y, m);
            acc[r].x = fmaf(hx, w0.x, fmaf(hy, w1.x, acc[r].x));
            acc[r].y = fmaf(hx, w0.y, fmaf(hy, w1.y, acc[r].y));
        }
    }
    if (w == 0) {
        const float2 bb = ((const float2*)bm1)[l];
        #pragma unroll
        for (int r = 0; r < 2; ++r) { acc[r].x += bb.x; acc[r].y += bb.y; }
    }
    float2* pre2 = (float2*)pre;
    #pragma unroll
    for (int r = 0; r < 2; ++r)
        pre2[(row0 + r) * 192 + w * 64 + l] = acc[r];
}

// ---------------------------------------------------------------------------
// K2 (fused): 1024 blocks x 4 waves; block = 2 rows x 2 j-halves.
// Wave (r,hf): softmax logits for its 128 j (lane owns 2 j), cross-wave
// combine via tiny LDS; phase B is BRANCH-FREE (masked j have w=0 exactly),
// so all preB loads pipeline. Halves reduced in LDS -> t[2][128]; then
// agg = t@Wm2 + bm2*sf and out = relu(hu + agg@Wu_bot + bu) computed
// col-split across all 256 threads (thread = (row, col)).
// ---------------------------------------------------------------------------
__global__ __launch_bounds__(256) void k2_main(
    const int* __restrict__ adj, const float* __restrict__ dist,
    const float* __restrict__ Wm1, const float* __restrict__ Wa,
    const float* __restrict__ pre,
    const float* __restrict__ aiv, const float* __restrict__ ajv,
    const float* __restrict__ Wm2, const float* __restrict__ bm2,
    const float* __restrict__ Wu,  const float* __restrict__ bu,
    float* __restrict__ out)
{
    const int tid  = threadIdx.x;
    const int l    = tid & 63;
    const int wid  = tid >> 6;
    const int r    = wid >> 1;          // row within block (0..1)
    const int hf   = wid & 1;           // j-half (0..1)
    const int row0 = blockIdx.x * 2;
    const int row  = row0 + r;
    const int b    = row >> 8;

    __shared__ float mx_sh[4], sm_sh[4], sf_sh[2];
    __shared__ float tp_sh[4][128];     // per-wave partial t
    __shared__ float t_sh[2][128];
    __shared__ float agg_sh[2][128];

    // ---- Phase A: masked softmax (lane owns j = hf*128 + 2l, +1) ----
    const float2 dv2 = ((const float2*)(dist + row * NN))[hf * 64 + l];
    const int2   mk2 = ((const int2*)  (adj  + row * NN))[hf * 64 + l];
    const float2 aj2 = ((const float2*)(ajv  + b   * NN))[hf * 64 + l];
    const float  ai  = aiv[row];
    const float  dc  = Wa[2 * DD];

    float l0 = ai + aj2.x + dv2.x * dc;
    float l1 = ai + aj2.y + dv2.y * dc;
    l0 = (l0 >= 0.f) ? l0 : 0.2f * l0;
    l1 = (l1 >= 0.f) ? l1 : 0.2f * l1;

    float m = fmaxf(mk2.x ? l0 : -1e9f, mk2.y ? l1 : -1e9f);
    #pragma unroll
    for (int o = 1; o < 64; o <<= 1) m = fmaxf(m, __shfl_xor(m, o, 64));
    if (l == 0) mx_sh[wid] = m;
    __syncthreads();
    const float mx = fmaxf(mx_sh[r * 2], mx_sh[r * 2 + 1]);

    const float e0 = mk2.x ? __expf(l0 - mx) : 0.f;
    const float e1 = mk2.y ? __expf(l1 - mx) : 0.f;
    float s = e0 + e1;
    #pragma unroll
    for (int o = 1; o < 64; o <<= 1) s += __shfl_xor(s, o, 64);
    if (l == 0) sm_sh[wid] = s;
    __syncthreads();
    const float esum = sm_sh[r * 2] + sm_sh[r * 2 + 1];
    const float inv  = (esum > 0.f) ? (1.0f / esum) : 0.f;
    const float w0 = e0 * inv, w1 = e1 * inv;   // exactly 0 for masked j

    // ---- Phase B: branch-free weighted relu accumulation over 128 j ----
    const float2* pre2 = (const float2*)pre;
    const float2  pa   = pre2[row * 192 + l];                   // preA+bm1
    const float2  wd1  = ((const float2*)Wm1)[2 * DD * 64 + l]; // d-coef row
    const float2* pBb  = pre2 + (size_t)b * NN * 192 + 64 + (size_t)hf * 128 * 192;

    float2 acc = make_float2(0.f, 0.f);
    #pragma unroll 8
    for (int p = 0; p < 64; ++p) {
        const float w0p = bcastf(w0, p);
        const float w1p = bcastf(w1, p);
        const float d0p = bcastf(dv2.x, p);
        const float d1p = bcastf(dv2.y, p);
        const float2 pb0 = pBb[(2 * p) * 192 + l];
        const float2 pb1 = pBb[(2 * p + 1) * 192 + l];
        float vx = fmaf(d0p, wd1.x, pa.x + pb0.x);
        float vy = fmaf(d0p, wd1.y, pa.y + pb0.y);
        acc.x = fmaf(w0p, fmaxf(vx, 0.f), acc.x);
        acc.y = fmaf(w0p, fmaxf(vy, 0.f), acc.y);
        vx = fmaf(d1p, wd1.x, pa.x + pb1.x);
        vy = fmaf(d1p, wd1.y, pa.y + pb1.y);
        acc.x = fmaf(w1p, fmaxf(vx, 0.f), acc.x);
        acc.y = fmaf(w1p, fmaxf(vy, 0.f), acc.y);
    }
    tp_sh[wid][2 * l]     = acc.x;
    tp_sh[wid][2 * l + 1] = acc.y;
    if (l == 0 && hf == 0) sf_sh[r] = (esum > 0.f) ? 1.f : 0.f;
    __syncthreads();

    // combine the two j-half partials
    {
        const int rr = tid >> 7, cc = tid & 127;
        t_sh[rr][cc] = tp_sh[rr * 2][cc] + tp_sh[rr * 2 + 1][cc];
    }
    __syncthreads();

    // ---- Phase C: agg = t @ Wm2 + bm2*sf (thread = (row, col)) ----
    const int r2 = tid >> 7, c = tid & 127;
    float av = 0.f;
    #pragma unroll 8
    for (int k = 0; k < 128; ++k)
        av = fmaf(t_sh[r2][k], Wm2[k * OC + c], av);
    agg_sh[r2][c] = fmaf(bm2[c], sf_sh[r2], av);
    __syncthreads();

    // ---- Phase D: out = relu(hu + agg @ Wu_bot + bu) ----
    float ov = 0.f;
    #pragma unroll 8
    for (int k = 0; k < 128; ++k)
        ov = fmaf(agg_sh[r2][k], Wu[(DD + k) * OC + c], ov);
    const float hu = pre[(row0 + r2) * 384 + 256 + c];
    out[(row0 + r2) * OC + c] = fmaxf(ov + hu + bu[c], 0.f);
}

extern "C" void kernel_launch(void* const* d_in, const int* in_sizes, int n_in,
                              void* d_out, int out_size, void* d_ws, size_t ws_size,
                              hipStream_t stream) {
    const float* h    = (const float*)d_in[0];
    const int*   adj  = (const int*)  d_in[1];
    const float* dist = (const float*)d_in[2];
    const float* Wm1  = (const float*)d_in[3];
    const float* bm1  = (const float*)d_in[4];
    const float* Wm2  = (const float*)d_in[5];
    const float* bm2  = (const float*)d_in[6];
    const float* Wa   = (const float*)d_in[7];
    const float* ba   = (const float*)d_in[8];
    const float* Wu   = (const float*)d_in[9];
    const float* bu   = (const float*)d_in[10];
    float* out = (float*)d_out;

    float* pre = (float*)d_ws;                    // 2048*384 f32 = 3 MB
    float* aiv = pre + 2048 * 384;                // 2048
    float* ajv = aiv + 2048;                      // 2048

    k1_pre <<<1024, 256, 0, stream>>>(h, Wm1, Wa, bm1, Wu, ba, pre, aiv, ajv);
    k2_main<<<1024, 256, 0, stream>>>(adj, dist, Wm1, Wa, pre, aiv, ajv,
                                      Wm2, bm2, Wu, bu, out);
}

// Round 6
// 112.114 us; speedup vs baseline: 1.2203x; 1.0382x over previous
//
#include <hip/hip_runtime.h>

#define NN 256
#define DD 128
#define OC 128
// pre layout per row: [ preA+bm1 (128) | preB (128) | h@Wu_top (128) ] = 384 f32

__device__ __forceinline__ float bcastf(float x, int lane) {
    return __int_as_float(__builtin_amdgcn_readlane(__float_as_int(x), lane));
}

// ---------------------------------------------------------------------------
// K1: 1024 blocks x 4 waves; block = 2 rows. Waves 0-2 each compute one
// 128-col region for both rows using float4 weight loads that cover TWO
// weight rows per instruction: lane = (d-parity = l>>5, col-quad = l&31).
// Partial sums over even/odd d are combined with shfl_xor(32). Wave 3: ai/aj.
// Regions: 0 = h@Wm1_top + bm1, 1 = h@Wm1_bot, 2 = h@Wu_top.
// ---------------------------------------------------------------------------
__global__ __launch_bounds__(256, 4) void k1_pre(
    const float* __restrict__ h, const float* __restrict__ Wm1,
    const float* __restrict__ Wa, const float* __restrict__ bm1,
    const float* __restrict__ Wu, const float* __restrict__ ba,
    float* __restrict__ pre, float* __restrict__ aiv, float* __restrict__ ajv)
{
    const int tid  = threadIdx.x;
    const int l    = tid & 63;
    const int w    = tid >> 6;
    const int row0 = blockIdx.x * 2;

    const float2* h2 = (const float2*)h;
    const float2 hr0 = h2[row0 * 64 + l];
    const float2 hr1 = h2[(row0 + 1) * 64 + l];

    if (w == 3) {
        const float2* Wa2 = (const float2*)Wa;
        const float2 wt = Wa2[l], wb = Wa2[64 + l];
        float vi0 = hr0.x * wt.x + hr0.y * wt.y;
        float vj0 = hr0.x * wb.x + hr0.y * wb.y;
        float vi1 = hr1.x * wt.x + hr1.y * wt.y;
        float vj1 = hr1.x * wb.x + hr1.y * wb.y;
        #pragma unroll
        for (int o = 1; o < 64; o <<= 1) {
            vi0 += __shfl_xor(vi0, o, 64);
            vj0 += __shfl_xor(vj0, o, 64);
            vi1 += __shfl_xor(vi1, o, 64);
            vj1 += __shfl_xor(vj1, o, 64);
        }
        if (l == 0) {
            const float b0 = ba[0];
            aiv[row0]     = vi0 + b0;  ajv[row0]     = vj0;
            aiv[row0 + 1] = vi1 + b0;  ajv[row0 + 1] = vj1;
        }
        return;
    }

    const float* Wbase = (w == 0) ? Wm1 : (w == 1) ? (Wm1 + DD * OC) : Wu;
    const float4* W4 = (const float4*)Wbase;
    const int dsel = l >> 5;          // which of the 2 d-rows this lane covers
    const int q    = l & 31;          // col quad

    float4 a0 = {0.f, 0.f, 0.f, 0.f};
    float4 a1 = {0.f, 0.f, 0.f, 0.f};
    #pragma unroll 8
    for (int i = 0; i < 64; ++i) {
        const float4 wv = W4[(2 * i + dsel) * 32 + q];
        const float h0e = bcastf(hr0.x, i), h0o = bcastf(hr0.y, i);
        const float h1e = bcastf(hr1.x, i), h1o = bcastf(hr1.y, i);
        const float hx0 = dsel ? h0o : h0e;
        const float hx1 = dsel ? h1o : h1e;
        a0.x = fmaf(hx0, wv.x, a0.x); a0.y = fmaf(hx0, wv.y, a0.y);
        a0.z = fmaf(hx0, wv.z, a0.z); a0.w = fmaf(hx0, wv.w, a0.w);
        a1.x = fmaf(hx1, wv.x, a1.x); a1.y = fmaf(hx1, wv.y, a1.y);
        a1.z = fmaf(hx1, wv.z, a1.z); a1.w = fmaf(hx1, wv.w, a1.w);
    }
    // combine even-d / odd-d partials across the half-wave split
    a0.x += __shfl_xor(a0.x, 32, 64); a0.y += __shfl_xor(a0.y, 32, 64);
    a0.z += __shfl_xor(a0.z, 32, 64); a0.w += __shfl_xor(a0.w, 32, 64);
    a1.x += __shfl_xor(a1.x, 32, 64); a1.y += __shfl_xor(a1.y, 32, 64);
    a1.z += __shfl_xor(a1.z, 32, 64); a1.w += __shfl_xor(a1.w, 32, 64);

    if (l < 32) {
        if (w == 0) {
            const float4 bb = ((const float4*)bm1)[q];
            a0.x += bb.x; a0.y += bb.y; a0.z += bb.z; a0.w += bb.w;
            a1.x += bb.x; a1.y += bb.y; a1.z += bb.z; a1.w += bb.w;
        }
        float4* pre4 = (float4*)pre;         // pre row = 384 floats = 96 float4
        pre4[row0 * 96 + w * 32 + q]       = a0;
        pre4[(row0 + 1) * 96 + w * 32 + q] = a1;
    }
}

// ---------------------------------------------------------------------------
// K2 (fused): 2048 blocks x 4 waves; block = 1 row (8 blocks/CU -> full occ).
// Wave wid owns j in [64*wid, 64*wid+64): softmax lane-per-j (butterfly +
// tiny LDS combine), then branch-free phase B over its 64 j (w=0 for masked).
// Phase C/D: thread = (k-half, col); weights streamed coalesced, t/agg read
// via LDS broadcast; partials combined through LDS.
// ---------------------------------------------------------------------------
__global__ __launch_bounds__(256, 8) void k2_main(
    const int* __restrict__ adj, const float* __restrict__ dist,
    const float* __restrict__ Wm1, const float* __restrict__ Wa,
    const float* __restrict__ pre,
    const float* __restrict__ aiv, const float* __restrict__ ajv,
    const float* __restrict__ Wm2, const float* __restrict__ bm2,
    const float* __restrict__ Wu,  const float* __restrict__ bu,
    float* __restrict__ out)
{
    const int tid = threadIdx.x;
    const int l   = tid & 63;
    const int wid = tid >> 6;
    const int row = blockIdx.x;
    const int b   = row >> 8;

    __shared__ float mx_sh[4], sm_sh[4];
    __shared__ float tp_sh[4][128];
    __shared__ float t_sh[128];
    __shared__ float agg_sh[128];

    // ---- Phase A: masked softmax, lane owns j = 64*wid + l ----
    const int   j  = 64 * wid + l;
    const float dv = dist[row * NN + j];
    const int   mk = adj[row * NN + j];
    const float ajl = ajv[b * NN + j];
    const float ai  = aiv[row];
    const float dc  = Wa[2 * DD];

    float lg = ai + ajl + dv * dc;
    lg = (lg >= 0.f) ? lg : 0.2f * lg;                 // leaky_relu(0.2)

    float m = mk ? lg : -1e9f;
    #pragma unroll
    for (int o = 1; o < 64; o <<= 1) m = fmaxf(m, __shfl_xor(m, o, 64));
    if (l == 0) mx_sh[wid] = m;
    __syncthreads();
    const float mx = fmaxf(fmaxf(mx_sh[0], mx_sh[1]), fmaxf(mx_sh[2], mx_sh[3]));

    const float e = mk ? __expf(lg - mx) : 0.f;
    float s = e;
    #pragma unroll
    for (int o = 1; o < 64; o <<= 1) s += __shfl_xor(s, o, 64);
    if (l == 0) sm_sh[wid] = s;
    __syncthreads();
    const float esum = sm_sh[0] + sm_sh[1] + sm_sh[2] + sm_sh[3];
    const float inv  = (esum > 0.f) ? (1.0f / esum) : 0.f;
    const float wj   = e * inv;                        // exactly 0 for masked j
    const float sf   = (esum > 0.f) ? 1.f : 0.f;       // uniform across block

    // ---- Phase B: branch-free weighted relu over this wave's 64 j ----
    const float2* pre2 = (const float2*)pre;
    const float2  pa   = pre2[row * 192 + l];                   // preA+bm1
    const float2  wd1  = ((const float2*)Wm1)[2 * DD * 64 + l]; // d-coef row
    const float2* pBb  = pre2 + (size_t)b * NN * 192 + 64;      // preB region
    const int     jb   = 64 * wid;

    float2 acc = {0.f, 0.f};
    #pragma unroll 8
    for (int p = 0; p < 64; ++p) {
        const float wp = bcastf(wj, p);
        const float dp = bcastf(dv, p);
        const float2 pb = pBb[(jb + p) * 192 + l];
        const float vx = fmaf(dp, wd1.x, pa.x + pb.x);
        const float vy = fmaf(dp, wd1.y, pa.y + pb.y);
        acc.x = fmaf(wp, fmaxf(vx, 0.f), acc.x);
        acc.y = fmaf(wp, fmaxf(vy, 0.f), acc.y);
    }
    tp_sh[wid][2 * l]     = acc.x;
    tp_sh[wid][2 * l + 1] = acc.y;
    __syncthreads();
    if (tid < 128)
        t_sh[tid] = tp_sh[0][tid] + tp_sh[1][tid] + tp_sh[2][tid] + tp_sh[3][tid];
    __syncthreads();

    // ---- Phase C: agg = t @ Wm2 + bm2*sf (thread = (k-half, col)) ----
    const int kh = tid >> 7, c = tid & 127;
    float pc = 0.f;
    #pragma unroll 8
    for (int k = 0; k < 64; ++k) {
        const int kk = 64 * kh + k;
        pc = fmaf(t_sh[kk], Wm2[kk * OC + c], pc);
    }
    tp_sh[kh][c] = pc;
    __syncthreads();
    if (tid < 128) agg_sh[tid] = tp_sh[0][tid] + tp_sh[1][tid] + bm2[tid] * sf;
    __syncthreads();

    // ---- Phase D: out = relu(hu + agg @ Wu_bot + bu) ----
    float pd = 0.f;
    #pragma unroll 8
    for (int k = 0; k < 64; ++k) {
        const int kk = 64 * kh + k;
        pd = fmaf(agg_sh[kk], Wu[(DD + kk) * OC + c], pd);
    }
    tp_sh[kh][c] = pd;
    __syncthreads();
    if (tid < 128) {
        const float hu = pre[row * 384 + 256 + tid];
        out[row * OC + tid] = fmaxf(tp_sh[0][tid] + tp_sh[1][tid] + hu + bu[tid], 0.f);
    }
}

extern "C" void kernel_launch(void* const* d_in, const int* in_sizes, int n_in,
                              void* d_out, int out_size, void* d_ws, size_t ws_size,
                              hipStream_t stream) {
    const float* h    = (const float*)d_in[0];
    const int*   adj  = (const int*)  d_in[1];
    const float* dist = (const float*)d_in[2];
    const float* Wm1  = (const float*)d_in[3];
    const float* bm1  = (const float*)d_in[4];
    const float* Wm2  = (const float*)d_in[5];
    const float* bm2  = (const float*)d_in[6];
    const float* Wa   = (const float*)d_in[7];
    const float* ba   = (const float*)d_in[8];
    const float* Wu   = (const float*)d_in[9];
    const float* bu   = (const float*)d_in[10];
    float* out = (float*)d_out;

    float* pre = (float*)d_ws;                    // 2048*384 f32 = 3 MB
    float* aiv = pre + 2048 * 384;                // 2048
    float* ajv = aiv + 2048;                      // 2048

    k1_pre <<<1024, 256, 0, stream>>>(h, Wm1, Wa, bm1, Wu, ba, pre, aiv, ajv);
    k2_main<<<2048, 256, 0, stream>>>(adj, dist, Wm1, Wa, pre, aiv, ajv,
                                      Wm2, bm2, Wu, bu, out);
}

// Round 7
// 109.893 us; speedup vs baseline: 1.2450x; 1.0202x over previous
//
#include <hip/hip_runtime.h>

#define NN 256
#define DD 128
#define OC 128
// pre layout per row: [ preA+bm1 (128) | preB (128) | h@Wu_top (128) ] = 384 f32
//   float4 view: row*96 + {0|32|64} + q

__device__ __forceinline__ float bcastf(float x, int lane) {
    return __int_as_float(__builtin_amdgcn_readlane(__float_as_int(x), lane));
}

// ---------------------------------------------------------------------------
// K1: 256 blocks x 4 waves; block = 8 rows. Waves 0-2 each compute one
// 128-col region for all 8 rows (float4 weight loads covering two d-rows:
// lane = (dsel = l>>5, colquad q = l&31); even/odd-d partials combined by
// shfl_xor(32)). Wave 3: ai/aj dot products. No LDS, no barriers.
// Regions: 0 = h@Wm1_top + bm1, 1 = h@Wm1_bot, 2 = h@Wu_top.
// ---------------------------------------------------------------------------
__global__ __launch_bounds__(256, 2) void k1_pre(
    const float* __restrict__ h, const float* __restrict__ Wm1,
    const float* __restrict__ Wa, const float* __restrict__ bm1,
    const float* __restrict__ Wu, const float* __restrict__ ba,
    float* __restrict__ pre, float* __restrict__ aiv, float* __restrict__ ajv)
{
    const int tid  = threadIdx.x;
    const int l    = tid & 63;
    const int w    = tid >> 6;
    const int row0 = blockIdx.x * 8;

    const float2* h2 = (const float2*)h;
    float2 hr[8];
    #pragma unroll
    for (int r = 0; r < 8; ++r) hr[r] = h2[(row0 + r) * 64 + l];

    if (w == 3) {
        const float2* Wa2 = (const float2*)Wa;
        const float2 wt = Wa2[l], wb = Wa2[64 + l];
        float vi[8], vj[8];
        #pragma unroll
        for (int r = 0; r < 8; ++r) {
            vi[r] = hr[r].x * wt.x + hr[r].y * wt.y;
            vj[r] = hr[r].x * wb.x + hr[r].y * wb.y;
        }
        #pragma unroll
        for (int o = 1; o < 64; o <<= 1) {
            #pragma unroll
            for (int r = 0; r < 8; ++r) {
                vi[r] += __shfl_xor(vi[r], o, 64);
                vj[r] += __shfl_xor(vj[r], o, 64);
            }
        }
        if (l == 0) {
            const float b0 = ba[0];
            #pragma unroll
            for (int r = 0; r < 8; ++r) {
                aiv[row0 + r] = vi[r] + b0;
                ajv[row0 + r] = vj[r];
            }
        }
        return;
    }

    const float* Wbase = (w == 0) ? Wm1 : (w == 1) ? (Wm1 + DD * OC) : Wu;
    const float4* W4 = (const float4*)Wbase;
    const int dsel = l >> 5;          // which of the 2 d-rows this lane covers
    const int q    = l & 31;          // col quad

    float4 a[8];
    #pragma unroll
    for (int r = 0; r < 8; ++r) a[r] = make_float4(0.f, 0.f, 0.f, 0.f);

    #pragma unroll 4
    for (int i = 0; i < 64; ++i) {
        const float4 wv = W4[(2 * i + dsel) * 32 + q];
        #pragma unroll
        for (int r = 0; r < 8; ++r) {
            const float he = bcastf(hr[r].x, i);
            const float ho = bcastf(hr[r].y, i);
            const float hx = dsel ? ho : he;
            a[r].x = fmaf(hx, wv.x, a[r].x);
            a[r].y = fmaf(hx, wv.y, a[r].y);
            a[r].z = fmaf(hx, wv.z, a[r].z);
            a[r].w = fmaf(hx, wv.w, a[r].w);
        }
    }
    #pragma unroll
    for (int r = 0; r < 8; ++r) {
        a[r].x += __shfl_xor(a[r].x, 32, 64);
        a[r].y += __shfl_xor(a[r].y, 32, 64);
        a[r].z += __shfl_xor(a[r].z, 32, 64);
        a[r].w += __shfl_xor(a[r].w, 32, 64);
    }

    if (l < 32) {
        if (w == 0) {
            const float4 bb = ((const float4*)bm1)[q];
            #pragma unroll
            for (int r = 0; r < 8; ++r) {
                a[r].x += bb.x; a[r].y += bb.y; a[r].z += bb.z; a[r].w += bb.w;
            }
        }
        float4* pre4 = (float4*)pre;        // pre row = 384 floats = 96 float4
        #pragma unroll
        for (int r = 0; r < 8; ++r)
            pre4[(row0 + r) * 96 + w * 32 + q] = a[r];
    }
}

// ---------------------------------------------------------------------------
// K2 (fused): 256 blocks x 8 waves (512 thr); block = 8 rows of one batch.
// Stage 1: the batch's full preB slice (256x128 f32 = 128 KB) -> LDS once.
// Stage 2: wave = row: register softmax (lane owns 4 j, butterfly reduce),
//          then branch-free phase B reading preB from LDS (2-way aliasing,
//          free). t[8][128] -> LDS.
// Stage 3: agg = t@Wm2 + bm2*sf, out = relu(hu + agg@Wu_bot + bu); thread =
//          (row-pair, col), weights read once per 8 rows.
// ---------------------------------------------------------------------------
__global__ __launch_bounds__(512, 2) void k2_main(
    const int* __restrict__ adj, const float* __restrict__ dist,
    const float* __restrict__ Wm1, const float* __restrict__ Wa,
    const float* __restrict__ pre,
    const float* __restrict__ aiv, const float* __restrict__ ajv,
    const float* __restrict__ Wm2, const float* __restrict__ bm2,
    const float* __restrict__ Wu,  const float* __restrict__ bu,
    float* __restrict__ out)
{
    const int tid  = threadIdx.x;
    const int l    = tid & 63;
    const int wid  = tid >> 6;          // 0..7 = row within block
    const int row0 = blockIdx.x * 8;
    const int row  = row0 + wid;
    const int b    = row0 >> 8;         // batch (blocks never straddle batches)

    __shared__ float pB[NN][128];       // 128 KB: preB slice of this batch
    __shared__ float t_sh[8][128];
    __shared__ float agg_sh[8][128];
    __shared__ float sf_sh[8];

    // ---- stage preB -> LDS (coalesced float4) ----
    {
        const float4* pre4 = (const float4*)pre;
        const int q  = tid & 31;        // float4 within row
        const int jr = tid >> 5;        // 0..15
        #pragma unroll
        for (int it = 0; it < 16; ++it) {
            const int j = jr * 16 + it;
            ((float4*)pB[j])[q] = pre4[(b * NN + j) * 96 + 32 + q];
        }
    }

    // ---- softmax (wave-local, lane owns j = 4l..4l+3) ----
    const int4   mk4 = ((const int4*)  (adj  + row * NN))[l];
    const float4 dv4 = ((const float4*)(dist + row * NN))[l];
    const float4 aj4 = ((const float4*)(ajv  + b   * NN))[l];
    const float  ai  = aiv[row];
    const float  dc  = Wa[2 * DD];

    float lg0 = ai + aj4.x + dv4.x * dc;
    float lg1 = ai + aj4.y + dv4.y * dc;
    float lg2 = ai + aj4.z + dv4.z * dc;
    float lg3 = ai + aj4.w + dv4.w * dc;
    lg0 = (lg0 >= 0.f) ? lg0 : 0.2f * lg0;
    lg1 = (lg1 >= 0.f) ? lg1 : 0.2f * lg1;
    lg2 = (lg2 >= 0.f) ? lg2 : 0.2f * lg2;
    lg3 = (lg3 >= 0.f) ? lg3 : 0.2f * lg3;

    float m = fmaxf(fmaxf(mk4.x ? lg0 : -1e9f, mk4.y ? lg1 : -1e9f),
                    fmaxf(mk4.z ? lg2 : -1e9f, mk4.w ? lg3 : -1e9f));
    #pragma unroll
    for (int o = 1; o < 64; o <<= 1) m = fmaxf(m, __shfl_xor(m, o, 64));

    const float e0 = mk4.x ? __expf(lg0 - m) : 0.f;
    const float e1 = mk4.y ? __expf(lg1 - m) : 0.f;
    const float e2 = mk4.z ? __expf(lg2 - m) : 0.f;
    const float e3 = mk4.w ? __expf(lg3 - m) : 0.f;
    float s = e0 + e1 + e2 + e3;
    #pragma unroll
    for (int o = 1; o < 64; o <<= 1) s += __shfl_xor(s, o, 64);
    const float inv = (s > 0.f) ? (1.0f / s) : 0.f;
    const float w0 = e0 * inv, w1 = e1 * inv, w2 = e2 * inv, w3 = e3 * inv;
    if (l == 0) sf_sh[wid] = (s > 0.f) ? 1.f : 0.f;

    // ---- phase B: branch-free weighted relu over 256 j, preB from LDS ----
    const float2* pre2 = (const float2*)pre;
    const float2  pa   = pre2[row * 192 + l];                   // preA+bm1
    const float2  wd1  = ((const float2*)Wm1)[2 * DD * 64 + l]; // d-coef row
    __syncthreads();                    // preB staged

    float2 acc = {0.f, 0.f};
    #define PHB(WW, DV, CC)                                          \
    {                                                                \
        _Pragma("unroll 8")                                          \
        for (int p = 0; p < 64; ++p) {                               \
            const float wp = bcastf(WW, p);                          \
            const float dp = bcastf(DV, p);                          \
            const float2 pb = ((const float2*)pB[4 * p + CC])[l];    \
            const float vx = fmaf(dp, wd1.x, pa.x + pb.x);           \
            const float vy = fmaf(dp, wd1.y, pa.y + pb.y);           \
            acc.x = fmaf(wp, fmaxf(vx, 0.f), acc.x);                 \
            acc.y = fmaf(wp, fmaxf(vy, 0.f), acc.y);                 \
        }                                                            \
    }
    PHB(w0, dv4.x, 0)
    PHB(w1, dv4.y, 1)
    PHB(w2, dv4.z, 2)
    PHB(w3, dv4.w, 3)
    #undef PHB

    t_sh[wid][2 * l]     = acc.x;
    t_sh[wid][2 * l + 1] = acc.y;
    __syncthreads();

    // ---- phase C: agg = t @ Wm2 + bm2*sf (thread = (row-pair, col)) ----
    const int c  = tid & 127;
    const int rh = tid >> 7;            // 0..3 -> rows rh, rh+4
    float c0 = 0.f, c1 = 0.f;
    #pragma unroll 8
    for (int k = 0; k < 128; ++k) {
        const float wv = Wm2[k * OC + c];
        c0 = fmaf(t_sh[rh][k],     wv, c0);
        c1 = fmaf(t_sh[rh + 4][k], wv, c1);
    }
    const float bmc = bm2[c];
    agg_sh[rh][c]     = fmaf(bmc, sf_sh[rh],     c0);
    agg_sh[rh + 4][c] = fmaf(bmc, sf_sh[rh + 4], c1);
    __syncthreads();

    // ---- phase D: out = relu(hu + agg @ Wu_bot + bu) ----
    float d0 = 0.f, d1 = 0.f;
    #pragma unroll 8
    for (int k = 0; k < 128; ++k) {
        const float wv = Wu[(DD + k) * OC + c];
        d0 = fmaf(agg_sh[rh][k],     wv, d0);
        d1 = fmaf(agg_sh[rh + 4][k], wv, d1);
    }
    const float buc = bu[c];
    const float hu0 = pre[(row0 + rh) * 384 + 256 + c];
    const float hu1 = pre[(row0 + rh + 4) * 384 + 256 + c];
    out[(row0 + rh) * OC + c]     = fmaxf(d0 + hu0 + buc, 0.f);
    out[(row0 + rh + 4) * OC + c] = fmaxf(d1 + hu1 + buc, 0.f);
}

extern "C" void kernel_launch(void* const* d_in, const int* in_sizes, int n_in,
                              void* d_out, int out_size, void* d_ws, size_t ws_size,
                              hipStream_t stream) {
    const float* h    = (const float*)d_in[0];
    const int*   adj  = (const int*)  d_in[1];
    const float* dist = (const float*)d_in[2];
    const float* Wm1  = (const float*)d_in[3];
    const float* bm1  = (const float*)d_in[4];
    const float* Wm2  = (const float*)d_in[5];
    const float* bm2  = (const float*)d_in[6];
    const float* Wa   = (const float*)d_in[7];
    const float* ba   = (const float*)d_in[8];
    const float* Wu   = (const float*)d_in[9];
    const float* bu   = (const float*)d_in[10];
    float* out = (float*)d_out;

    float* pre = (float*)d_ws;                    // 2048*384 f32 = 3 MB
    float* aiv = pre + 2048 * 384;                // 2048
    float* ajv = aiv + 2048;                      // 2048

    k1_pre <<<256, 256, 0, stream>>>(h, Wm1, Wa, bm1, Wu, ba, pre, aiv, ajv);
    k2_main<<<256, 512, 0, stream>>>(adj, dist, Wm1, Wa, pre, aiv, ajv,
                                     Wm2, bm2, Wu, bu, out);
}

// Round 8
// 108.316 us; speedup vs baseline: 1.2631x; 1.0146x over previous
//
#include <hip/hip_runtime.h>

#define NN 256
#define DD 128
#define OC 128
// ws layout: pre[2048][256] f32 = [preA+bm1 (128) | h@Wu_top (128)]  (2 MB)
//            pbB[2048][128] bf16 (packed ushort)                     (512 KB)
//            aiv[2048], ajv[2048] f32

__device__ __forceinline__ float bcastf(float x, int lane) {
    return __int_as_float(__builtin_amdgcn_readlane(__float_as_int(x), lane));
}
__device__ __forceinline__ unsigned short f2bf(float x) {
    unsigned int u = __float_as_uint(x);
    u = (u + 0x7fffu + ((u >> 16) & 1u)) >> 16;   // round-to-nearest-even
    return (unsigned short)u;
}

// ---------------------------------------------------------------------------
// K1: 512 blocks x 4 waves; block = 4 rows. Waves 0-2 each compute one
// 128-col region for all 4 rows (float4 weight loads covering two d-rows:
// lane = (dsel = l>>5, colquad q = l&31); even/odd-d partials combined by
// shfl_xor(32)). Wave 3: ai/aj dots. Regions: 0 = h@Wm1_top + bm1 (f32),
// 1 = h@Wm1_bot -> bf16 pbB, 2 = h@Wu_top (f32). No LDS, no barriers.
// ---------------------------------------------------------------------------
__global__ __launch_bounds__(256, 4) void k1_pre(
    const float* __restrict__ h, const float* __restrict__ Wm1,
    const float* __restrict__ Wa, const float* __restrict__ bm1,
    const float* __restrict__ Wu, const float* __restrict__ ba,
    float* __restrict__ pre, unsigned short* __restrict__ pbB,
    float* __restrict__ aiv, float* __restrict__ ajv)
{
    const int tid  = threadIdx.x;
    const int l    = tid & 63;
    const int w    = tid >> 6;
    const int row0 = blockIdx.x * 4;

    const float2* h2 = (const float2*)h;
    float2 hr[4];
    #pragma unroll
    for (int r = 0; r < 4; ++r) hr[r] = h2[(row0 + r) * 64 + l];

    if (w == 3) {
        const float2* Wa2 = (const float2*)Wa;
        const float2 wt = Wa2[l], wb = Wa2[64 + l];
        float vi[4], vj[4];
        #pragma unroll
        for (int r = 0; r < 4; ++r) {
            vi[r] = hr[r].x * wt.x + hr[r].y * wt.y;
            vj[r] = hr[r].x * wb.x + hr[r].y * wb.y;
        }
        #pragma unroll
        for (int o = 1; o < 64; o <<= 1) {
            #pragma unroll
            for (int r = 0; r < 4; ++r) {
                vi[r] += __shfl_xor(vi[r], o, 64);
                vj[r] += __shfl_xor(vj[r], o, 64);
            }
        }
        if (l == 0) {
            const float b0 = ba[0];
            #pragma unroll
            for (int r = 0; r < 4; ++r) {
                aiv[row0 + r] = vi[r] + b0;
                ajv[row0 + r] = vj[r];
            }
        }
        return;
    }

    const float* Wbase = (w == 0) ? Wm1 : (w == 1) ? (Wm1 + DD * OC) : Wu;
    const float4* W4 = (const float4*)Wbase;
    const int dsel = l >> 5;
    const int q    = l & 31;

    float4 a[4];
    #pragma unroll
    for (int r = 0; r < 4; ++r) a[r] = make_float4(0.f, 0.f, 0.f, 0.f);

    #pragma unroll 8
    for (int i = 0; i < 64; ++i) {
        const float4 wv = W4[(2 * i + dsel) * 32 + q];
        #pragma unroll
        for (int r = 0; r < 4; ++r) {
            const float he = bcastf(hr[r].x, i);
            const float ho = bcastf(hr[r].y, i);
            const float hx = dsel ? ho : he;
            a[r].x = fmaf(hx, wv.x, a[r].x);
            a[r].y = fmaf(hx, wv.y, a[r].y);
            a[r].z = fmaf(hx, wv.z, a[r].z);
            a[r].w = fmaf(hx, wv.w, a[r].w);
        }
    }
    #pragma unroll
    for (int r = 0; r < 4; ++r) {
        a[r].x += __shfl_xor(a[r].x, 32, 64);
        a[r].y += __shfl_xor(a[r].y, 32, 64);
        a[r].z += __shfl_xor(a[r].z, 32, 64);
        a[r].w += __shfl_xor(a[r].w, 32, 64);
    }

    if (l < 32) {
        if (w == 1) {                       // preB -> bf16
            #pragma unroll
            for (int r = 0; r < 4; ++r) {
                ushort4 p;
                p.x = f2bf(a[r].x); p.y = f2bf(a[r].y);
                p.z = f2bf(a[r].z); p.w = f2bf(a[r].w);
                ((ushort4*)pbB)[(row0 + r) * 32 + q] = p;
            }
        } else {
            float4* pre4 = (float4*)pre;    // pre row = 256 f32 = 64 float4
            const int roff = (w == 0) ? 0 : 32;
            if (w == 0) {
                const float4 bb = ((const float4*)bm1)[q];
                #pragma unroll
                for (int r = 0; r < 4; ++r) {
                    a[r].x += bb.x; a[r].y += bb.y;
                    a[r].z += bb.z; a[r].w += bb.w;
                }
            }
            #pragma unroll
            for (int r = 0; r < 4; ++r)
                pre4[(row0 + r) * 64 + roff + q] = a[r];
        }
    }
}

// ---------------------------------------------------------------------------
// K2 (fused): 512 blocks x 8 waves (512 thr); block = 4 rows x 2 j-halves.
// Stage: batch's preB slice (256x128 bf16 = 64 KB) -> LDS once.
// Softmax: lane owns 2 j, butterfly + cross-wave pair combine.
// Phase B: branch-free weighted relu over this wave's 128 j; preB from LDS
// (uint per lane = 2 bf16 ch, 2-way bank aliasing = free).
// Phases C/D: thread = (row, col); weights read once per 4 rows.
// ---------------------------------------------------------------------------
__global__ __launch_bounds__(512, 4) void k2_main(
    const int* __restrict__ adj, const float* __restrict__ dist,
    const float* __restrict__ Wm1, const float* __restrict__ Wa,
    const float* __restrict__ pre, const unsigned short* __restrict__ pbB,
    const float* __restrict__ aiv, const float* __restrict__ ajv,
    const float* __restrict__ Wm2, const float* __restrict__ bm2,
    const float* __restrict__ Wu,  const float* __restrict__ bu,
    float* __restrict__ out)
{
    const int tid  = threadIdx.x;
    const int l    = tid & 63;
    const int wid  = tid >> 6;
    const int r    = wid >> 1;          // row within block (0..3)
    const int hf   = wid & 1;           // j-half
    const int row0 = blockIdx.x * 4;
    const int row  = row0 + r;
    const int b    = row0 >> 8;         // 64 blocks per batch, never straddle

    __shared__ unsigned int pB[NN * 64];    // 64 KB: bf16 preB slice (uint = 2ch)
    __shared__ float mx_sh[8], sm_sh[8], sf_sh[4];
    __shared__ float tp_sh[8][128];
    __shared__ float t_sh[4][128];
    __shared__ float agg_sh[4][128];

    // ---- stage preB -> LDS (uint4, coalesced) ----
    {
        const uint4* src = (const uint4*)(pbB + (size_t)b * NN * 128);
        uint4* dst = (uint4*)pB;
        #pragma unroll
        for (int it = 0; it < 8; ++it)
            dst[tid + 512 * it] = src[tid + 512 * it];
    }

    // ---- softmax: lane owns j = hf*128 + 2l, 2l+1 ----
    const int2   mk2 = ((const int2*)  (adj  + row * NN))[hf * 64 + l];
    const float2 dv2 = ((const float2*)(dist + row * NN))[hf * 64 + l];
    const float2 aj2 = ((const float2*)(ajv  + b   * NN))[hf * 64 + l];
    const float  ai  = aiv[row];
    const float  dc  = Wa[2 * DD];

    float l0 = ai + aj2.x + dv2.x * dc;
    float l1 = ai + aj2.y + dv2.y * dc;
    l0 = (l0 >= 0.f) ? l0 : 0.2f * l0;
    l1 = (l1 >= 0.f) ? l1 : 0.2f * l1;

    float m = fmaxf(mk2.x ? l0 : -1e9f, mk2.y ? l1 : -1e9f);
    #pragma unroll
    for (int o = 1; o < 64; o <<= 1) m = fmaxf(m, __shfl_xor(m, o, 64));
    if (l == 0) mx_sh[wid] = m;
    __syncthreads();
    const float mx = fmaxf(mx_sh[2 * r], mx_sh[2 * r + 1]);

    const float e0 = mk2.x ? __expf(l0 - mx) : 0.f;
    const float e1 = mk2.y ? __expf(l1 - mx) : 0.f;
    float s = e0 + e1;
    #pragma unroll
    for (int o = 1; o < 64; o <<= 1) s += __shfl_xor(s, o, 64);
    if (l == 0) sm_sh[wid] = s;
    __syncthreads();                    // also guarantees pB staged
    const float esum = sm_sh[2 * r] + sm_sh[2 * r + 1];
    const float inv  = (esum > 0.f) ? (1.0f / esum) : 0.f;
    const float w0 = e0 * inv, w1 = e1 * inv;   // exactly 0 for masked j
    if (l == 0 && hf == 0) sf_sh[r] = (esum > 0.f) ? 1.f : 0.f;

    // ---- phase B: branch-free weighted relu over this wave's 128 j ----
    const float2 pa  = ((const float2*)(pre + row * 256))[l];       // preA+bm1
    const float2 wd1 = ((const float2*)Wm1)[2 * DD * 64 + l];       // d-coef
    const unsigned int* pBh = pB + (hf * 128) * 64;

    float2 acc = {0.f, 0.f};
    #pragma unroll 8
    for (int p = 0; p < 64; ++p) {
        const float w0p = bcastf(w0, p);
        const float d0p = bcastf(dv2.x, p);
        const float w1p = bcastf(w1, p);
        const float d1p = bcastf(dv2.y, p);
        const unsigned int u0 = pBh[(2 * p) * 64 + l];
        const unsigned int u1 = pBh[(2 * p + 1) * 64 + l];
        {
            const float pbx = __uint_as_float(u0 << 16);
            const float pby = __uint_as_float(u0 & 0xffff0000u);
            const float vx = fmaf(d0p, wd1.x, pa.x + pbx);
            const float vy = fmaf(d0p, wd1.y, pa.y + pby);
            acc.x = fmaf(w0p, fmaxf(vx, 0.f), acc.x);
            acc.y = fmaf(w0p, fmaxf(vy, 0.f), acc.y);
        }
        {
            const float pbx = __uint_as_float(u1 << 16);
            const float pby = __uint_as_float(u1 & 0xffff0000u);
            const float vx = fmaf(d1p, wd1.x, pa.x + pbx);
            const float vy = fmaf(d1p, wd1.y, pa.y + pby);
            acc.x = fmaf(w1p, fmaxf(vx, 0.f), acc.x);
            acc.y = fmaf(w1p, fmaxf(vy, 0.f), acc.y);
        }
    }
    tp_sh[wid][2 * l]     = acc.x;
    tp_sh[wid][2 * l + 1] = acc.y;
    __syncthreads();

    // combine the two j-half partials (512 threads = 4 rows x 128 ch)
    const int rr = tid >> 7, cc = tid & 127;
    t_sh[rr][cc] = tp_sh[2 * rr][cc] + tp_sh[2 * rr + 1][cc];
    __syncthreads();

    // ---- phase C: agg = t @ Wm2 + bm2*sf (thread = (row, col)) ----
    float av = 0.f;
    #pragma unroll 8
    for (int k = 0; k < 128; ++k)
        av = fmaf(t_sh[rr][k], Wm2[k * OC + cc], av);
    agg_sh[rr][cc] = fmaf(bm2[cc], sf_sh[rr], av);
    __syncthreads();

    // ---- phase D: out = relu(hu + agg @ Wu_bot + bu) ----
    float ov = 0.f;
    #pragma unroll 8
    for (int k = 0; k < 128; ++k)
        ov = fmaf(agg_sh[rr][k], Wu[(DD + k) * OC + cc], ov);
    const float hu = pre[(row0 + rr) * 256 + 128 + cc];
    out[(row0 + rr) * OC + cc] = fmaxf(ov + hu + bu[cc], 0.f);
}

extern "C" void kernel_launch(void* const* d_in, const int* in_sizes, int n_in,
                              void* d_out, int out_size, void* d_ws, size_t ws_size,
                              hipStream_t stream) {
    const float* h    = (const float*)d_in[0];
    const int*   adj  = (const int*)  d_in[1];
    const float* dist = (const float*)d_in[2];
    const float* Wm1  = (const float*)d_in[3];
    const float* bm1  = (const float*)d_in[4];
    const float* Wm2  = (const float*)d_in[5];
    const float* bm2  = (const float*)d_in[6];
    const float* Wa   = (const float*)d_in[7];
    const float* ba   = (const float*)d_in[8];
    const float* Wu   = (const float*)d_in[9];
    const float* bu   = (const float*)d_in[10];
    float* out = (float*)d_out;

    float*          pre = (float*)d_ws;                   // 2048*256 f32 = 2 MB
    unsigned short* pbB = (unsigned short*)(pre + 2048 * 256);  // 512 KB
    float*          aiv = (float*)(pbB + 2048 * 128);     // 2048
    float*          ajv = aiv + 2048;                     // 2048

    k1_pre <<<512, 256, 0, stream>>>(h, Wm1, Wa, bm1, Wu, ba, pre, pbB, aiv, ajv);
    k2_main<<<512, 512, 0, stream>>>(adj, dist, Wm1, Wa, pre, pbB, aiv, ajv,
                                     Wm2, bm2, Wu, bu, out);
}